// Round 12
// baseline (457.226 us; speedup 1.0000x reference)
//
#include <hip/hip_runtime.h>
#include <math.h>

#define N_TOK 2000
#define NH 8
#define HD 32
#define SCALE 25.0f
#define SIM_TH 0.75f
#define EPSF 1e-8f
#define NSLOT 8   // ceil(2000/256)
#define NTAIL 208 // valid lanes in slot 7: 2000 - 7*256
#define SPAD 2048 // padded s_attn stride

typedef _Float16 half2_t __attribute__((ext_vector_type(2)));

__device__ __forceinline__ unsigned rflu(unsigned u) {
  return (unsigned)__builtin_amdgcn_readfirstlane((int)u);
}
__device__ __forceinline__ half2_t u2h(unsigned u) {
  return __builtin_bit_cast(half2_t, u);
}
__device__ __forceinline__ unsigned h2u(half2_t h) {
  return __builtin_bit_cast(unsigned, h);
}

// f32 += f16x2 . f16x2 (v_dot2_f32_f16; products exact, fp32 accumulate)
__device__ __forceinline__ float fdot2f(unsigned a, unsigned b, float c) {
#if __has_builtin(__builtin_amdgcn_fdot2)
  return __builtin_amdgcn_fdot2(u2h(a), u2h(b), c, false);
#else
  const half2_t ha = u2h(a), hb = u2h(b);
  return c + (float)ha.x * (float)hb.x + (float)ha.y * (float)hb.y;
#endif
}

__device__ __forceinline__ float block_max256(float v, float* red) {
#pragma unroll
  for (int off = 32; off > 0; off >>= 1) v = fmaxf(v, __shfl_xor(v, off, 64));
  __syncthreads();
  if ((threadIdx.x & 63) == 0) red[threadIdx.x >> 6] = v;
  __syncthreads();
  return fmaxf(fmaxf(red[0], red[1]), fmaxf(red[2], red[3]));
}
__device__ __forceinline__ float block_sum256(float v, float* red) {
#pragma unroll
  for (int off = 32; off > 0; off >>= 1) v += __shfl_xor(v, off, 64);
  __syncthreads();
  if ((threadIdx.x & 63) == 0) red[threadIdx.x >> 6] = v;
  __syncthreads();
  return (red[0] + red[1]) + (red[2] + red[3]);
}

// load a query pair's packed-f16 row into uniform uints (SGPRs)
#define LOAD_QPAIR(BUF)                                                   \
  {                                                                       \
    const uint4* __restrict__ qb = (const uint4*)(BUF) + (size_t)h * 4 * N_TOK; \
    _Pragma("unroll") for (int gg = 0; gg < 4; gg++) {                    \
      const uint4 a0 = qb[gg * N_TOK + i0];                               \
      const uint4 a1 = qb[gg * N_TOK + i1];                               \
      qp0[4 * gg + 0] = rflu(a0.x); qp0[4 * gg + 1] = rflu(a0.y);         \
      qp0[4 * gg + 2] = rflu(a0.z); qp0[4 * gg + 3] = rflu(a0.w);         \
      qp1[4 * gg + 0] = rflu(a1.x); qp1[4 * gg + 1] = rflu(a1.y);         \
      qp1[4 * gg + 2] = rflu(a1.z); qp1[4 * gg + 3] = rflu(a1.w);         \
    }                                                                     \
  }

// ---------------------------------------------------------------------------
// Kernel 1: QKV projection + l2norm; f16 normalized planes, fp32 v_rm, and
// NEW: f16 raw-V transposed plane vt_h [h][d][m] for the PV loop.
// grid = (500, 2), block = 256
// ---------------------------------------------------------------------------
__global__ __launch_bounds__(256) void qkv_norm_kernel(
    const float* __restrict__ x_cls, const float* __restrict__ x_reg,
    const float* __restrict__ W_cls, const float* __restrict__ W_reg,
    _Float16* __restrict__ qc_h, _Float16* __restrict__ qr_h,
    _Float16* __restrict__ kc_h, _Float16* __restrict__ kr_h,
    _Float16* __restrict__ vn_h, float* __restrict__ v_rm,
    _Float16* __restrict__ vt_h) {
  __shared__ float xs[4][256];
  __shared__ float res[4][768];
  __shared__ float inv_norm[96];

  const int n0 = blockIdx.x * 4;
  const int which = blockIdx.y;
  const int tid = threadIdx.x;
  const float* __restrict__ x = which ? x_reg : x_cls;
  const float* __restrict__ W = which ? W_reg : W_cls;

#pragma unroll
  for (int r = 0; r < 4; r++) xs[r][tid] = x[(n0 + r) * 256 + tid];
  __syncthreads();

  float acc[4][3];
#pragma unroll
  for (int r = 0; r < 4; r++) acc[r][0] = acc[r][1] = acc[r][2] = 0.f;

  for (int k = 0; k < 256; k++) {
    const float* __restrict__ wr = W + k * 768;
    const float w0 = wr[tid], w1 = wr[tid + 256], w2 = wr[tid + 512];
#pragma unroll
    for (int r = 0; r < 4; r++) {
      const float xv = xs[r][k];
      acc[r][0] += xv * w0;
      acc[r][1] += xv * w1;
      acc[r][2] += xv * w2;
    }
  }
#pragma unroll
  for (int r = 0; r < 4; r++) {
    res[r][tid] = acc[r][0];
    res[r][tid + 256] = acc[r][1];
    res[r][tid + 512] = acc[r][2];
  }
  __syncthreads();

  if (tid < 96) {
    const int r = tid / 24, grp = tid % 24;
    float ss = 0.f;
#pragma unroll
    for (int d = 0; d < HD; d++) {
      const float v = res[r][grp * 32 + d];
      ss += v * v;
    }
    inv_norm[tid] = 1.0f / (sqrtf(ss) + EPSF);
  }
  __syncthreads();

#pragma unroll
  for (int j = 0; j < 3; j++) {
    const int c = tid + j * 256;
    const int qkv = c >> 8, grp = c >> 5;
    const int h = grp & 7, d = c & 31;
    const int gg = d >> 3, dd = d & 7;
#pragma unroll
    for (int r = 0; r < 4; r++) {
      const int n = n0 + r;
      const float val = res[r][c];
      const float nval = val * inv_norm[r * 24 + grp];
      const size_t fi = ((size_t)(h * 4 + gg) * N_TOK + n) * 8 + dd;
      if (qkv == 0) {
        (which ? qr_h : qc_h)[fi] = (_Float16)nval;
      } else if (qkv == 1) {
        (which ? kr_h : kc_h)[fi] = (_Float16)nval;
      } else if (which == 0) {
        v_rm[(h * N_TOK + n) * HD + d] = val;
        vn_h[fi] = (_Float16)nval;
        vt_h[(size_t)(h * HD + d) * N_TOK + n] = (_Float16)val;
      }
    }
  }
}

// ---------------------------------------------------------------------------
// Kernel 2: round-11 structure with (a) conflict-free PV slice mapping
// (m = mb*128 + slice*4: av-read banks disjoint across wave slices),
// (b) f16 m-contiguous V (uint2 loads + fdot2 with f16 attn weights;
// PV traffic and VALU both cut), (c) part4 stride 9 (2-way max, free).
// grid = 1000, block = 256
// ---------------------------------------------------------------------------
__global__ __launch_bounds__(256) void attn12_kernel(
    const _Float16* __restrict__ qc_h, const _Float16* __restrict__ qr_h,
    const _Float16* __restrict__ kc_h, const _Float16* __restrict__ kr_h,
    const _Float16* __restrict__ vn_h, const float* __restrict__ v_rm,
    const _Float16* __restrict__ vt_h,
    float* __restrict__ out_x, float* __restrict__ out_sim) {
  __shared__ float s_attn[2][SPAD];     // padded; tail stays 0 for PV
  __shared__ float s_union[4000];       // er (C/R->combine) / part4 (PV)
  __shared__ float red[4];

  float* __restrict__ s_er = s_union;
  float4* __restrict__ part4 = (float4*)s_union;  // stride-9 indexing, 576 used

  const int tid = threadIdx.x;
  const int i0 = blockIdx.x * 2;
  const int i1 = i0 + 1;
  const int bs = (i0 / 10) * 10;  // i0 even -> i0,i1 share the same decade

  float sim0[NSLOT], sim1[NSLOT], raw0[NSLOT], raw1[NSLOT];
#pragma unroll
  for (int t = 0; t < NSLOT; t++) {
    sim0[t] = 0.f; sim1[t] = 0.f; raw0[t] = 0.f; raw1[t] = 0.f;
  }
  // zero the PV padding tail once (combine only writes m<2000)
  if (tid < SPAD - N_TOK) {
    s_attn[0][N_TOK + tid] = 0.f;
    s_attn[1][N_TOK + tid] = 0.f;
  }
  __syncthreads();

  unsigned qp0[16], qp1[16];  // packed f16 query pairs, wave-uniform -> SGPR

  // pipelined sweep over the 8 m-slots of one f16 K plane: emit(t,d0,d1)
  auto sweep = [&](const uint4* __restrict__ kt4, auto&& emit) {
    uint4 ka[4], kb[4];
#pragma unroll
    for (int g_ = 0; g_ < 4; g_++) ka[g_] = kt4[g_ * N_TOK + tid];  // t=0
#pragma unroll
    for (int t = 0; t < NSLOT; t++) {
      if (t < NSLOT - 1) {  // prefetch t+1 while computing t
        const int m1 = tid + 256 * (t + 1);
        const bool v1 = (t + 1 < 7) || (tid < NTAIL);
        const int mc1 = v1 ? m1 : (N_TOK - 1);
#pragma unroll
        for (int g_ = 0; g_ < 4; g_++) kb[g_] = kt4[g_ * N_TOK + mc1];
      }
      float d0 = 0.f, d1 = 0.f;
#pragma unroll
      for (int g_ = 0; g_ < 4; g_++) {
        d0 = fdot2f(ka[g_].x, qp0[4 * g_ + 0], d0);
        d0 = fdot2f(ka[g_].y, qp0[4 * g_ + 1], d0);
        d0 = fdot2f(ka[g_].z, qp0[4 * g_ + 2], d0);
        d0 = fdot2f(ka[g_].w, qp0[4 * g_ + 3], d0);
        d1 = fdot2f(ka[g_].x, qp1[4 * g_ + 0], d1);
        d1 = fdot2f(ka[g_].y, qp1[4 * g_ + 1], d1);
        d1 = fdot2f(ka[g_].z, qp1[4 * g_ + 2], d1);
        d1 = fdot2f(ka[g_].w, qp1[4 * g_ + 3], d1);
      }
      emit(t, d0, d1);
#pragma unroll
      for (int g_ = 0; g_ < 4; g_++) ka[g_] = kb[g_];
    }
  };

  for (int hh = 0; hh < NH; hh++) {
    const int h = (blockIdx.x + hh) & 7;  // XCD-local head schedule

    // ===== phase C: cls scores -> e = exp(s-25) -> s_attn + running sum ===
    LOAD_QPAIR(qc_h);
    float ls0 = 0.f, ls1 = 0.f;
    sweep((const uint4*)kc_h + (size_t)h * 4 * N_TOK,
          [&](int t, float d0, float d1) {
            const int m = tid + 256 * t;
            const bool valid = (t < 7) || (tid < NTAIL);
            const float e0 = valid ? __expf(d0 * SCALE - SCALE) : 0.f;
            const float e1 = valid ? __expf(d1 * SCALE - SCALE) : 0.f;
            ls0 += e0; ls1 += e1;
            if (valid) {
              s_attn[0][m] = e0;
              s_attn[1][m] = e1;
            }
          });
    const float S0c = block_sum256(ls0, red);
    const float S1c = block_sum256(ls1, red);
    const float n0c = 0.5f / S0c, n1c = 0.5f / S1c;

    // ===== phase R: reg scores -> s_er (own slots only) =====
    LOAD_QPAIR(qr_h);
    float lr0 = 0.f, lr1 = 0.f;
    sweep((const uint4*)kr_h + (size_t)h * 4 * N_TOK,
          [&](int t, float d0, float d1) {
            const int m = tid + 256 * t;
            const bool valid = (t < 7) || (tid < NTAIL);
            const float e0 = valid ? __expf(d0 * SCALE - SCALE) : 0.f;
            const float e1 = valid ? __expf(d1 * SCALE - SCALE) : 0.f;
            lr0 += e0; lr1 += e1;
            if (valid) {
              s_er[m] = e0;
              s_er[N_TOK + m] = e1;
            }
          });
    const float S0r = block_sum256(lr0, red);
    const float S1r = block_sum256(lr1, red);
    const float n0r = 0.5f / S0r, n1r = 0.5f / S1r;

    // ===== combine, mask, sim += =====
#pragma unroll
    for (int t = 0; t < NSLOT; t++) {
      const int m = tid + 256 * t;
      if ((t < 7) || (tid < NTAIL)) {
        float a0 = s_attn[0][m] * n0c + s_er[m] * n0r;
        float a1 = s_attn[1][m] * n1c + s_er[N_TOK + m] * n1r;
        if (m >= bs && m < bs + 9) {
          if (m != i0) a0 = 0.f;
          if (m != i1) a1 = 0.f;
        }
        s_attn[0][m] = a0;
        s_attn[1][m] = a1;
        sim0[t] += a0;
        sim1[t] += a1;
      }
    }

    // ===== phase V: vn cosine -> raw += =====
    LOAD_QPAIR(vn_h);
    sweep((const uint4*)vn_h + (size_t)h * 4 * N_TOK,
          [&](int t, float d0, float d1) {
            const bool valid = (t < 7) || (tid < NTAIL);
            if (valid) { raw0[t] += d0; raw1[t] += d1; }
          });
    __syncthreads();  // s_attn final; s_er reads done -> part4 may reuse

    // ===== attn @ V : f16 m-contiguous V, conflict-free slice mapping =====
    {
      const int g2 = tid & 7, slice = tid >> 3;
      float acc0[4] = {0.f, 0.f, 0.f, 0.f};
      float acc1[4] = {0.f, 0.f, 0.f, 0.f};
      const _Float16* __restrict__ vbase = vt_h + (size_t)h * HD * N_TOK;
#pragma unroll 4
      for (int mb = 0; mb < 16; mb++) {
        const int m = mb * 128 + slice * 4;       // bank = slice*4: disjoint
        const int mv = (m < N_TOK) ? m : (N_TOK - 4);  // clamp (NaN guard)
        const float4 av0 = *(const float4*)&s_attn[0][m];
        const float4 av1 = *(const float4*)&s_attn[1][m];
        const unsigned a0lo = h2u((half2_t){(_Float16)av0.x, (_Float16)av0.y});
        const unsigned a0hi = h2u((half2_t){(_Float16)av0.z, (_Float16)av0.w});
        const unsigned a1lo = h2u((half2_t){(_Float16)av1.x, (_Float16)av1.y});
        const unsigned a1hi = h2u((half2_t){(_Float16)av1.z, (_Float16)av1.w});
        uint2 vv[4];
#pragma unroll
        for (int dd = 0; dd < 4; dd++) {
          vv[dd] = *(const uint2*)(vbase + (size_t)(g2 * 4 + dd) * N_TOK + mv);
        }
#pragma unroll
        for (int dd = 0; dd < 4; dd++) {
          acc0[dd] = fdot2f(vv[dd].x, a0lo, acc0[dd]);
          acc0[dd] = fdot2f(vv[dd].y, a0hi, acc0[dd]);
          acc1[dd] = fdot2f(vv[dd].x, a1lo, acc1[dd]);
          acc1[dd] = fdot2f(vv[dd].y, a1hi, acc1[dd]);
        }
      }
      __syncthreads();  // all s_er/combine reads long done
      part4[(slice * 2 + 0) * 9 + g2] =
          (float4){acc0[0], acc0[1], acc0[2], acc0[3]};
      part4[(slice * 2 + 1) * 9 + g2] =
          (float4){acc1[0], acc1[1], acc1[2], acc1[3]};
    }
    __syncthreads();
    if (tid < 16) {
      const int q = tid >> 3, g = tid & 7;
      float4 s = {0.f, 0.f, 0.f, 0.f};
#pragma unroll 8
      for (int sl = 0; sl < 32; sl++) {
        const float4 p = part4[(sl * 2 + q) * 9 + g];
        s.x += p.x; s.y += p.y; s.z += p.z; s.w += p.w;
      }
      const int irow = q ? i1 : i0;
      *(float4*)(out_x + (size_t)irow * 512 + h * 32 + 4 * g) = s;
    } else if (tid >= 64 && tid < 128) {
      const int q = (tid - 64) >> 5, d = (tid - 64) & 31;
      const int irow = q ? i1 : i0;
      out_x[(size_t)irow * 512 + 256 + h * 32 + d] =
          v_rm[((size_t)h * N_TOK + irow) * HD + d];
    }
    __syncthreads();  // part4 reads done -> s_er reuse next head
  }

  // ===== sim_round2 epilogue, from registers =====
#pragma unroll
  for (int q = 0; q < 2; q++) {
    const int irow = q ? i1 : i0;
    float* __restrict__ sim = q ? sim1 : sim0;
    float* __restrict__ raw = q ? raw1 : raw0;

    float lm = -1e30f;
#pragma unroll
    for (int t = 0; t < NSLOT; t++) {
      if ((t < 7) || (tid < NTAIL)) lm = fmaxf(lm, sim[t] * 0.125f);
    }
    const float M = block_max256(lm, red);

    float ls = 0.f;
#pragma unroll
    for (int t = 0; t < NSLOT; t++) {
      const bool valid = (t < 7) || (tid < NTAIL);
      const float e = valid ? __expf(sim[t] * 0.125f - M) : 0.f;
      sim[t] = e;
      ls += e;
    }
    const float S = block_sum256(ls, red);
    const float invS = 1.0f / S;

    float lms = 0.f;
#pragma unroll
    for (int t = 0; t < NSLOT; t++) {
      const bool valid = (t < 7) || (tid < NTAIL);
      const float p = sim[t] * invS;
      const float mp = (valid && (raw[t] * 0.125f > SIM_TH)) ? p : 0.f;
      sim[t] = mp;
      lms += mp;
    }
    const float MS = block_sum256(lms, red);
    const float invMS = 1.0f / (MS + EPSF);

#pragma unroll
    for (int t = 0; t < NSLOT; t++) {
      const int m = tid + 256 * t;
      if ((t < 7) || (tid < NTAIL)) {
        out_sim[(size_t)irow * N_TOK + m] = sim[t] * invMS;
      }
    }
  }
}

// ---------------------------------------------------------------------------
extern "C" void kernel_launch(void* const* d_in, const int* in_sizes, int n_in,
                              void* d_out, int out_size, void* d_ws,
                              size_t ws_size, hipStream_t stream) {
  const float* x_cls = (const float*)d_in[0];
  const float* x_reg = (const float*)d_in[1];
  const float* W_cls = (const float*)d_in[2];
  const float* W_reg = (const float*)d_in[3];

  // ws layout: v_rm fp32, then six f16 plane buffers (vt_h NOT last so any
  // clamped-adjacent reads stay well inside the workspace)
  const size_t seg = (size_t)NH * N_TOK * HD;  // 512000 elements
  float* v_rm = (float*)d_ws;
  _Float16* vt_h = (_Float16*)(v_rm + seg);
  _Float16* qc_h = vt_h + seg;
  _Float16* qr_h = qc_h + seg;
  _Float16* kc_h = qr_h + seg;
  _Float16* kr_h = kc_h + seg;
  _Float16* vn_h = kr_h + seg;

  dim3 g1(500, 2);
  qkv_norm_kernel<<<g1, 256, 0, stream>>>(x_cls, x_reg, W_cls, W_reg, qc_h,
                                          qr_h, kc_h, kr_h, vn_h, v_rm, vt_h);

  float* out_x = (float*)d_out;                  // [2000, 512]
  float* out_sim = out_x + (size_t)N_TOK * 512;  // [2000, 2000]
  attn12_kernel<<<1000, 256, 0, stream>>>(qc_h, qr_h, kc_h, kr_h, vn_h, v_rm,
                                          vt_h, out_x, out_sim);
}

// Round 13
// 349.062 us; speedup vs baseline: 1.3099x; 1.3099x over previous
//
#include <hip/hip_runtime.h>
#include <math.h>

#define N_TOK 2000
#define NH 8
#define HD 32
#define SCALE 25.0f
#define SIM_TH 0.75f
#define EPSF 1e-8f
#define NSLOT 8   // ceil(2000/256)
#define NTAIL 208 // valid lanes in slot 7: 2000 - 7*256
#define SPAD 2048 // padded s_attn stride

typedef _Float16 half2_t __attribute__((ext_vector_type(2)));

__device__ __forceinline__ unsigned rflu(unsigned u) {
  return (unsigned)__builtin_amdgcn_readfirstlane((int)u);
}
__device__ __forceinline__ half2_t u2h(unsigned u) {
  return __builtin_bit_cast(half2_t, u);
}

// f32 += f16x2 . f16x2 (v_dot2_f32_f16; products exact, fp32 accumulate)
__device__ __forceinline__ float fdot2f(unsigned a, unsigned b, float c) {
#if __has_builtin(__builtin_amdgcn_fdot2)
  return __builtin_amdgcn_fdot2(u2h(a), u2h(b), c, false);
#else
  const half2_t ha = u2h(a), hb = u2h(b);
  return c + (float)ha.x * (float)hb.x + (float)ha.y * (float)hb.y;
#endif
}

__device__ __forceinline__ float block_max256(float v, float* red) {
#pragma unroll
  for (int off = 32; off > 0; off >>= 1) v = fmaxf(v, __shfl_xor(v, off, 64));
  __syncthreads();
  if ((threadIdx.x & 63) == 0) red[threadIdx.x >> 6] = v;
  __syncthreads();
  return fmaxf(fmaxf(red[0], red[1]), fmaxf(red[2], red[3]));
}
__device__ __forceinline__ float block_sum256(float v, float* red) {
#pragma unroll
  for (int off = 32; off > 0; off >>= 1) v += __shfl_xor(v, off, 64);
  __syncthreads();
  if ((threadIdx.x & 63) == 0) red[threadIdx.x >> 6] = v;
  __syncthreads();
  return (red[0] + red[1]) + (red[2] + red[3]);
}

// load a query pair's packed-f16 row into uniform uints (SGPRs)
#define LOAD_QPAIR(BUF)                                                   \
  {                                                                       \
    const uint4* __restrict__ qb = (const uint4*)(BUF) + (size_t)h * 4 * N_TOK; \
    _Pragma("unroll") for (int gg = 0; gg < 4; gg++) {                    \
      const uint4 a0 = qb[gg * N_TOK + i0];                               \
      const uint4 a1 = qb[gg * N_TOK + i1];                               \
      qp0[4 * gg + 0] = rflu(a0.x); qp0[4 * gg + 1] = rflu(a0.y);         \
      qp0[4 * gg + 2] = rflu(a0.z); qp0[4 * gg + 3] = rflu(a0.w);         \
      qp1[4 * gg + 0] = rflu(a1.x); qp1[4 * gg + 1] = rflu(a1.y);         \
      qp1[4 * gg + 2] = rflu(a1.z); qp1[4 * gg + 3] = rflu(a1.w);         \
    }                                                                     \
  }

// ---------------------------------------------------------------------------
// Kernel 1: QKV projection + l2norm; f16 normalized planes + fp32 v_rm.
// grid = (500, 2), block = 256
// ---------------------------------------------------------------------------
__global__ __launch_bounds__(256) void qkv_norm_kernel(
    const float* __restrict__ x_cls, const float* __restrict__ x_reg,
    const float* __restrict__ W_cls, const float* __restrict__ W_reg,
    _Float16* __restrict__ qc_h, _Float16* __restrict__ qr_h,
    _Float16* __restrict__ kc_h, _Float16* __restrict__ kr_h,
    _Float16* __restrict__ vn_h, float* __restrict__ v_rm) {
  __shared__ float xs[4][256];
  __shared__ float res[4][768];
  __shared__ float inv_norm[96];

  const int n0 = blockIdx.x * 4;
  const int which = blockIdx.y;
  const int tid = threadIdx.x;
  const float* __restrict__ x = which ? x_reg : x_cls;
  const float* __restrict__ W = which ? W_reg : W_cls;

#pragma unroll
  for (int r = 0; r < 4; r++) xs[r][tid] = x[(n0 + r) * 256 + tid];
  __syncthreads();

  float acc[4][3];
#pragma unroll
  for (int r = 0; r < 4; r++) acc[r][0] = acc[r][1] = acc[r][2] = 0.f;

  for (int k = 0; k < 256; k++) {
    const float* __restrict__ wr = W + k * 768;
    const float w0 = wr[tid], w1 = wr[tid + 256], w2 = wr[tid + 512];
#pragma unroll
    for (int r = 0; r < 4; r++) {
      const float xv = xs[r][k];
      acc[r][0] += xv * w0;
      acc[r][1] += xv * w1;
      acc[r][2] += xv * w2;
    }
  }
#pragma unroll
  for (int r = 0; r < 4; r++) {
    res[r][tid] = acc[r][0];
    res[r][tid + 256] = acc[r][1];
    res[r][tid + 512] = acc[r][2];
  }
  __syncthreads();

  if (tid < 96) {
    const int r = tid / 24, grp = tid % 24;
    float ss = 0.f;
#pragma unroll
    for (int d = 0; d < HD; d++) {
      const float v = res[r][grp * 32 + d];
      ss += v * v;
    }
    inv_norm[tid] = 1.0f / (sqrtf(ss) + EPSF);
  }
  __syncthreads();

#pragma unroll
  for (int j = 0; j < 3; j++) {
    const int c = tid + j * 256;
    const int qkv = c >> 8, grp = c >> 5;
    const int h = grp & 7, d = c & 31;
    const int gg = d >> 3, dd = d & 7;
#pragma unroll
    for (int r = 0; r < 4; r++) {
      const int n = n0 + r;
      const float val = res[r][c];
      const float nval = val * inv_norm[r * 24 + grp];
      const size_t fi = ((size_t)(h * 4 + gg) * N_TOK + n) * 8 + dd;
      if (qkv == 0) {
        (which ? qr_h : qc_h)[fi] = (_Float16)nval;
      } else if (qkv == 1) {
        (which ? kr_h : kc_h)[fi] = (_Float16)nval;
      } else if (which == 0) {
        v_rm[(h * N_TOK + n) * HD + d] = val;
        vn_h[fi] = (_Float16)nval;
      }
    }
  }
}

// ---------------------------------------------------------------------------
// Kernel 2: round-11 structure (f16 score streams, pipelined sweeps, fp32 V
// PV) with ONLY the bank-conflict fixes kept from round 12's experiment:
// (a) rotated PV m-order: m = slice*64 + 4*((j+slice)&15) -> av-read start
// bank = 4*((j+slice)%8), disjoint across a wave's 8 slices (conflict-free,
// identical data path); (b) part4 at stride 9 (2-way max). The f16-V PV of
// round 12 REGRESSED (268->383us: halved bytes/request + cvt dep-chain) and
// is reverted.
// grid = 1000, block = 256
// ---------------------------------------------------------------------------
__global__ __launch_bounds__(256) void attn13_kernel(
    const _Float16* __restrict__ qc_h, const _Float16* __restrict__ qr_h,
    const _Float16* __restrict__ kc_h, const _Float16* __restrict__ kr_h,
    const _Float16* __restrict__ vn_h, const float* __restrict__ v_rm,
    float* __restrict__ out_x, float* __restrict__ out_sim) {
  __shared__ float s_attn[2][SPAD];     // padded; tail stays 0 for PV
  __shared__ float s_union[4000];       // er (C/R->combine) / part4 (PV)
  __shared__ float red[4];

  float* __restrict__ s_er = s_union;
  float4* __restrict__ part4 = (float4*)s_union;  // stride-9 indexing

  const int tid = threadIdx.x;
  const int i0 = blockIdx.x * 2;
  const int i1 = i0 + 1;
  const int bs = (i0 / 10) * 10;  // i0 even -> i0,i1 share the same decade

  float sim0[NSLOT], sim1[NSLOT], raw0[NSLOT], raw1[NSLOT];
#pragma unroll
  for (int t = 0; t < NSLOT; t++) {
    sim0[t] = 0.f; sim1[t] = 0.f; raw0[t] = 0.f; raw1[t] = 0.f;
  }
  // zero the PV padding tail once (combine only writes m<2000)
  if (tid < SPAD - N_TOK) {
    s_attn[0][N_TOK + tid] = 0.f;
    s_attn[1][N_TOK + tid] = 0.f;
  }
  __syncthreads();

  unsigned qp0[16], qp1[16];  // packed f16 query pairs, wave-uniform -> SGPR

  // pipelined sweep over the 8 m-slots of one f16 K plane: emit(t,d0,d1)
  auto sweep = [&](const uint4* __restrict__ kt4, auto&& emit) {
    uint4 ka[4], kb[4];
#pragma unroll
    for (int g_ = 0; g_ < 4; g_++) ka[g_] = kt4[g_ * N_TOK + tid];  // t=0
#pragma unroll
    for (int t = 0; t < NSLOT; t++) {
      if (t < NSLOT - 1) {  // prefetch t+1 while computing t
        const int m1 = tid + 256 * (t + 1);
        const bool v1 = (t + 1 < 7) || (tid < NTAIL);
        const int mc1 = v1 ? m1 : (N_TOK - 1);
#pragma unroll
        for (int g_ = 0; g_ < 4; g_++) kb[g_] = kt4[g_ * N_TOK + mc1];
      }
      float d0 = 0.f, d1 = 0.f;
#pragma unroll
      for (int g_ = 0; g_ < 4; g_++) {
        d0 = fdot2f(ka[g_].x, qp0[4 * g_ + 0], d0);
        d0 = fdot2f(ka[g_].y, qp0[4 * g_ + 1], d0);
        d0 = fdot2f(ka[g_].z, qp0[4 * g_ + 2], d0);
        d0 = fdot2f(ka[g_].w, qp0[4 * g_ + 3], d0);
        d1 = fdot2f(ka[g_].x, qp1[4 * g_ + 0], d1);
        d1 = fdot2f(ka[g_].y, qp1[4 * g_ + 1], d1);
        d1 = fdot2f(ka[g_].z, qp1[4 * g_ + 2], d1);
        d1 = fdot2f(ka[g_].w, qp1[4 * g_ + 3], d1);
      }
      emit(t, d0, d1);
#pragma unroll
      for (int g_ = 0; g_ < 4; g_++) ka[g_] = kb[g_];
    }
  };

  for (int hh = 0; hh < NH; hh++) {
    const int h = (blockIdx.x + hh) & 7;  // XCD-local head schedule

    // ===== phase C: cls scores -> e = exp(s-25) -> s_attn + running sum ===
    LOAD_QPAIR(qc_h);
    float ls0 = 0.f, ls1 = 0.f;
    sweep((const uint4*)kc_h + (size_t)h * 4 * N_TOK,
          [&](int t, float d0, float d1) {
            const int m = tid + 256 * t;
            const bool valid = (t < 7) || (tid < NTAIL);
            const float e0 = valid ? __expf(d0 * SCALE - SCALE) : 0.f;
            const float e1 = valid ? __expf(d1 * SCALE - SCALE) : 0.f;
            ls0 += e0; ls1 += e1;
            if (valid) {
              s_attn[0][m] = e0;
              s_attn[1][m] = e1;
            }
          });
    const float S0c = block_sum256(ls0, red);
    const float S1c = block_sum256(ls1, red);
    const float n0c = 0.5f / S0c, n1c = 0.5f / S1c;

    // ===== phase R: reg scores -> s_er (own slots only) =====
    LOAD_QPAIR(qr_h);
    float lr0 = 0.f, lr1 = 0.f;
    sweep((const uint4*)kr_h + (size_t)h * 4 * N_TOK,
          [&](int t, float d0, float d1) {
            const int m = tid + 256 * t;
            const bool valid = (t < 7) || (tid < NTAIL);
            const float e0 = valid ? __expf(d0 * SCALE - SCALE) : 0.f;
            const float e1 = valid ? __expf(d1 * SCALE - SCALE) : 0.f;
            lr0 += e0; lr1 += e1;
            if (valid) {
              s_er[m] = e0;
              s_er[N_TOK + m] = e1;
            }
          });
    const float S0r = block_sum256(lr0, red);
    const float S1r = block_sum256(lr1, red);
    const float n0r = 0.5f / S0r, n1r = 0.5f / S1r;

    // ===== combine, mask, sim += =====
#pragma unroll
    for (int t = 0; t < NSLOT; t++) {
      const int m = tid + 256 * t;
      if ((t < 7) || (tid < NTAIL)) {
        float a0 = s_attn[0][m] * n0c + s_er[m] * n0r;
        float a1 = s_attn[1][m] * n1c + s_er[N_TOK + m] * n1r;
        if (m >= bs && m < bs + 9) {
          if (m != i0) a0 = 0.f;
          if (m != i1) a1 = 0.f;
        }
        s_attn[0][m] = a0;
        s_attn[1][m] = a1;
        sim0[t] += a0;
        sim1[t] += a1;
      }
    }

    // ===== phase V: vn cosine -> raw += =====
    LOAD_QPAIR(vn_h);
    sweep((const uint4*)vn_h + (size_t)h * 4 * N_TOK,
          [&](int t, float d0, float d1) {
            const bool valid = (t < 7) || (tid < NTAIL);
            if (valid) { raw0[t] += d0; raw1[t] += d1; }
          });
    __syncthreads();  // s_attn final; s_er reads done -> part4 may reuse

    // ===== attn @ V : fp32 V, batch-4, rotated m-order (conflict-free) ====
    {
      const int g2 = tid & 7, slice = tid >> 3;
      const int m0 = slice * 64;
      float4 a0acc = {0.f, 0.f, 0.f, 0.f}, a1acc = {0.f, 0.f, 0.f, 0.f};
      const float4* __restrict__ v4 = (const float4*)v_rm + (size_t)h * N_TOK * 8;
#pragma unroll 4
      for (int j = 0; j < 16; j++) {
        const int m = m0 + 4 * ((j + slice) & 15);  // bank 4*((j+slice)%8)
        const float4 av0 = *(const float4*)&s_attn[0][m];
        const float4 av1 = *(const float4*)&s_attn[1][m];
        // pad rows (m>=2000) have a==0; OOB v4 reads stay inside d_ws and
        // are multiplied by 0 (f16 plane bytes can't form f32 NaN).
        const float4 vv0 = v4[(size_t)(m + 0) * 8 + g2];
        const float4 vv1 = v4[(size_t)(m + 1) * 8 + g2];
        const float4 vv2 = v4[(size_t)(m + 2) * 8 + g2];
        const float4 vv3 = v4[(size_t)(m + 3) * 8 + g2];
        a0acc.x += av0.x * vv0.x; a0acc.y += av0.x * vv0.y;
        a0acc.z += av0.x * vv0.z; a0acc.w += av0.x * vv0.w;
        a1acc.x += av1.x * vv0.x; a1acc.y += av1.x * vv0.y;
        a1acc.z += av1.x * vv0.z; a1acc.w += av1.x * vv0.w;
        a0acc.x += av0.y * vv1.x; a0acc.y += av0.y * vv1.y;
        a0acc.z += av0.y * vv1.z; a0acc.w += av0.y * vv1.w;
        a1acc.x += av1.y * vv1.x; a1acc.y += av1.y * vv1.y;
        a1acc.z += av1.y * vv1.z; a1acc.w += av1.y * vv1.w;
        a0acc.x += av0.z * vv2.x; a0acc.y += av0.z * vv2.y;
        a0acc.z += av0.z * vv2.z; a0acc.w += av0.z * vv2.w;
        a1acc.x += av1.z * vv2.x; a1acc.y += av1.z * vv2.y;
        a1acc.z += av1.z * vv2.z; a1acc.w += av1.z * vv2.w;
        a0acc.x += av0.w * vv3.x; a0acc.y += av0.w * vv3.y;
        a0acc.z += av0.w * vv3.z; a0acc.w += av0.w * vv3.w;
        a1acc.x += av1.w * vv3.x; a1acc.y += av1.w * vv3.y;
        a1acc.z += av1.w * vv3.z; a1acc.w += av1.w * vv3.w;
      }
      part4[(slice * 2 + 0) * 9 + g2] = a0acc;
      part4[(slice * 2 + 1) * 9 + g2] = a1acc;
    }
    __syncthreads();
    if (tid < 16) {
      const int q = tid >> 3, g = tid & 7;
      float4 s = {0.f, 0.f, 0.f, 0.f};
#pragma unroll 8
      for (int sl = 0; sl < 32; sl++) {
        const float4 p = part4[(sl * 2 + q) * 9 + g];
        s.x += p.x; s.y += p.y; s.z += p.z; s.w += p.w;
      }
      const int irow = q ? i1 : i0;
      *(float4*)(out_x + (size_t)irow * 512 + h * 32 + 4 * g) = s;
    } else if (tid >= 64 && tid < 128) {
      const int q = (tid - 64) >> 5, d = (tid - 64) & 31;
      const int irow = q ? i1 : i0;
      out_x[(size_t)irow * 512 + 256 + h * 32 + d] =
          v_rm[((size_t)h * N_TOK + irow) * HD + d];
    }
    __syncthreads();  // part4 reads done -> s_er reuse next head
  }

  // ===== sim_round2 epilogue, from registers =====
#pragma unroll
  for (int q = 0; q < 2; q++) {
    const int irow = q ? i1 : i0;
    float* __restrict__ sim = q ? sim1 : sim0;
    float* __restrict__ raw = q ? raw1 : raw0;

    float lm = -1e30f;
#pragma unroll
    for (int t = 0; t < NSLOT; t++) {
      if ((t < 7) || (tid < NTAIL)) lm = fmaxf(lm, sim[t] * 0.125f);
    }
    const float M = block_max256(lm, red);

    float ls = 0.f;
#pragma unroll
    for (int t = 0; t < NSLOT; t++) {
      const bool valid = (t < 7) || (tid < NTAIL);
      const float e = valid ? __expf(sim[t] * 0.125f - M) : 0.f;
      sim[t] = e;
      ls += e;
    }
    const float S = block_sum256(ls, red);
    const float invS = 1.0f / S;

    float lms = 0.f;
#pragma unroll
    for (int t = 0; t < NSLOT; t++) {
      const bool valid = (t < 7) || (tid < NTAIL);
      const float p = sim[t] * invS;
      const float mp = (valid && (raw[t] * 0.125f > SIM_TH)) ? p : 0.f;
      sim[t] = mp;
      lms += mp;
    }
    const float MS = block_sum256(lms, red);
    const float invMS = 1.0f / (MS + EPSF);

#pragma unroll
    for (int t = 0; t < NSLOT; t++) {
      const int m = tid + 256 * t;
      if ((t < 7) || (tid < NTAIL)) {
        out_sim[(size_t)irow * N_TOK + m] = sim[t] * invMS;
      }
    }
  }
}

// ---------------------------------------------------------------------------
extern "C" void kernel_launch(void* const* d_in, const int* in_sizes, int n_in,
                              void* d_out, int out_size, void* d_ws,
                              size_t ws_size, hipStream_t stream) {
  const float* x_cls = (const float*)d_in[0];
  const float* x_reg = (const float*)d_in[1];
  const float* W_cls = (const float*)d_in[2];
  const float* W_reg = (const float*)d_in[3];

  // ws layout: v_rm fp32 first (PV OOB-clamped reads land in f16 planes,
  // which cannot alias to f32 NaN), then five f16 plane buffers
  const size_t seg = (size_t)NH * N_TOK * HD;  // 512000 elements
  float* v_rm = (float*)d_ws;
  _Float16* qc_h = (_Float16*)(v_rm + seg);
  _Float16* qr_h = qc_h + seg;
  _Float16* kc_h = qr_h + seg;
  _Float16* kr_h = kc_h + seg;
  _Float16* vn_h = kr_h + seg;

  dim3 g1(500, 2);
  qkv_norm_kernel<<<g1, 256, 0, stream>>>(x_cls, x_reg, W_cls, W_reg, qc_h,
                                          qr_h, kc_h, kr_h, vn_h, v_rm);

  float* out_x = (float*)d_out;                  // [2000, 512]
  float* out_sim = out_x + (size_t)N_TOK * 512;  // [2000, 2000]
  attn13_kernel<<<1000, 256, 0, stream>>>(qc_h, qr_h, kc_h, kr_h, vn_h, v_rm,
                                          out_x, out_sim);
}